// Round 11
// baseline (6313.055 us; speedup 1.0000x reference)
//
#include <hip/hip_runtime.h>
#include <math.h>
#include <stdint.h>

// Problem constants
constexpr int LL = 4096;   // seq len
constexpr int EE = 300;    // embedding dim
constexpr int HH = 256;    // per-direction hidden (H2)
constexpr int NGATE = 1024;// 4*HH
constexpr int TT = 16;     // tagset
constexpr float NEGV = -10000.0f;

typedef _Float16 v2h __attribute__((ext_vector_type(2)));
typedef _Float16 v8h __attribute__((ext_vector_type(8)));
typedef float v4f __attribute__((ext_vector_type(4)));

// Workspace layout (byte offsets)
constexpr size_t OFF_X    = 16384;
constexpr size_t OFF_ZX   = OFF_X    + (size_t)LL*EE*4;     // 2*L*1024 f32
constexpr size_t OFF_HALL = OFF_ZX   + (size_t)2*LL*NGATE*4;// 2*L*256 f32
constexpr size_t OFF_FE   = OFF_HALL + (size_t)2*LL*HH*4;   // L*16 f32

__device__ __forceinline__ v2h pack_h2(float x, float y) {
  return __builtin_bit_cast(v2h, __builtin_amdgcn_cvt_pkrtz(x, y));
}
__device__ __forceinline__ unsigned pack_u(float x, float y) {
  return __builtin_bit_cast(unsigned, __builtin_amdgcn_cvt_pkrtz(x, y));
}
__device__ __forceinline__ v8h make_v8h(v2h a, v2h b, v2h c, v2h d) {
  union { v2h p[4]; v8h v; } u; u.p[0]=a; u.p[1]=b; u.p[2]=c; u.p[3]=d; return u.v;
}

__device__ __forceinline__ float fsigmoid(float x) {
  return __builtin_amdgcn_rcpf(1.f + __expf(-x));
}
__device__ __forceinline__ float ftanh(float x) {
  return 1.f - 2.f * __builtin_amdgcn_rcpf(1.f + __expf(2.f * x));
}

template <int CTRL>
__device__ __forceinline__ int dpp_i(int v) {
  return __builtin_amdgcn_mov_dpp(v, CTRL, 0xF, 0xF, true);
}
template <int CTRL>
__device__ __forceinline__ float dpp_f(float v) {
  return __int_as_float(__builtin_amdgcn_mov_dpp(__float_as_int(v), CTRL, 0xF, 0xF, true));
}
__device__ __forceinline__ float bperm_f(int lane, float v) {
  return __int_as_float(__builtin_amdgcn_ds_bpermute(lane << 2, __float_as_int(v)));
}

// ---------------------------------------------------------------------------
// Kernel 1: embedding gather
// ---------------------------------------------------------------------------
__global__ void gather_x(const int* __restrict__ sent, const float* __restrict__ emb,
                         float* __restrict__ X) {
  const int i = blockIdx.x * blockDim.x + threadIdx.x;
  const int total = LL * (EE / 4);
  if (i >= total) return;
  const int row = i / (EE / 4), c4 = i % (EE / 4);
  const int v = sent[row];
  reinterpret_cast<float4*>(X)[(size_t)row * (EE / 4) + c4] =
      reinterpret_cast<const float4*>(emb + (size_t)v * EE)[c4];
}

// ---------------------------------------------------------------------------
// Kernel 2: input GEMM, GATE-TRANSPOSED store: Zx[t][unit*4+gate]
// (unchanged — validated R5-R10)
// ---------------------------------------------------------------------------
__global__ __launch_bounds__(256) void input_gemm(
    const float* __restrict__ X, const float* __restrict__ w_f,
    const float* __restrict__ b_f, const float* __restrict__ w_b,
    const float* __restrict__ b_b, float* __restrict__ ZX) {
  const int dir = blockIdx.z;
  const float* __restrict__ W  = dir ? w_b : w_f;
  const float* __restrict__ Bv = dir ? b_b : b_f;
  float* __restrict__ Z = ZX + (size_t)dir * LL * NGATE;
  __shared__ float As[32][68];
  __shared__ float Bs[32][68];
  const int m0 = blockIdx.y * 64, n0 = blockIdx.x * 64;
  const int t = threadIdx.x;
  const int tx = t & 15, ty = t >> 4;
  float acc[4][4] = {};
  for (int k0 = 0; k0 < EE; k0 += 32) {
#pragma unroll
    for (int r = 0; r < 2; ++r) {
      const int idx = t + r * 256;
      const int row = idx >> 3;
      const int kk4 = (idx & 7) << 2;
      const int k = k0 + kk4;
      float4 va = make_float4(0.f, 0.f, 0.f, 0.f), vb = va;
      if (k < EE) {
        va = *reinterpret_cast<const float4*>(X + (size_t)(m0 + row) * EE + k);
        vb = *reinterpret_cast<const float4*>(W + (size_t)(n0 + row) * EE + k);
      }
      As[kk4 + 0][row] = va.x; As[kk4 + 1][row] = va.y;
      As[kk4 + 2][row] = va.z; As[kk4 + 3][row] = va.w;
      Bs[kk4 + 0][row] = vb.x; Bs[kk4 + 1][row] = vb.y;
      Bs[kk4 + 2][row] = vb.z; Bs[kk4 + 3][row] = vb.w;
    }
    __syncthreads();
    const int kmax = (EE - k0 < 32) ? (EE - k0) : 32;
    for (int k = 0; k < kmax; ++k) {
      const float4 av = *reinterpret_cast<const float4*>(&As[k][ty << 2]);
      const float4 bv = *reinterpret_cast<const float4*>(&Bs[k][tx << 2]);
      acc[0][0] += av.x * bv.x; acc[0][1] += av.x * bv.y; acc[0][2] += av.x * bv.z; acc[0][3] += av.x * bv.w;
      acc[1][0] += av.y * bv.x; acc[1][1] += av.y * bv.y; acc[1][2] += av.y * bv.z; acc[1][3] += av.y * bv.w;
      acc[2][0] += av.z * bv.x; acc[2][1] += av.z * bv.y; acc[2][2] += av.z * bv.z; acc[2][3] += av.z * bv.w;
      acc[3][0] += av.w * bv.x; acc[3][1] += av.w * bv.y; acc[3][2] += av.w * bv.z; acc[3][3] += av.w * bv.w;
    }
    __syncthreads();
  }
#pragma unroll
  for (int i = 0; i < 4; ++i)
#pragma unroll
    for (int j = 0; j < 4; ++j) {
      const int m = m0 + (ty << 2) + i, n = n0 + (tx << 2) + j;
      Z[(size_t)m * NGATE + (((n & 255) << 2) | (n >> 8))] = acc[i][j] + Bv[n];
    }
}

// ---------------------------------------------------------------------------
// Kernel 3: persistent bidirectional LSTM recurrence — all-MFMA, one WG per
// direction, lq-split gates (R10) + TWO-BLOCK GATE OVERLAP (R11).
//
// R10 post-mortem: 67% per-CU MfmaUtil, step 3037 cy vs 2483 MFMA floor.
// Remaining ~550 cy = serial tail: gates couldn't start until ALL 8 accs
// finished (the hi-select referenced every acc). R11: split into two blocks
// of two gate-pairs — block A computes tiles of gates i,f (kc 0-7, 4 accs)
// then ig,fg IMMEDIATELY; block B computes gates o,g then the short
// og/gg->c->h chain. Block A's gate VALU has no dep on block B's MFMAs, so
// the scheduler hoists ~620 cy of block-B MFMA issue over block A's gate
// chain — half the tail moves into the MFMA shadow. Cost: A-frags re-read
// once per block (+64 KB/step LDS -> 280 KB total ~2190 cy, still < 2483
// floor). LDS B-frags re-mapped one-odd-tile-per-pair (slots: i:0-4 f:5-9
// o:10-14 g:15-18) so each block has ~10 evenly-spread LDS reads (R8 fix
// preserved). Peak accs 8->~5: ~238 unified regs (safer than R10's ~250).
// Tiles: T = gate*2 + half; n = (T>>1)*256 + 32w + (T&1)*16 + lcol.
// Reg frags: T0,T2,T4,T6 all kc (32) + T1,T3,T7 kc5-7 (9) + T5 kc4-7 (4).
// One barrier/step; h16u parity dbuf; lq-split writers — all R10-verified.
// ---------------------------------------------------------------------------
__global__ __launch_bounds__(512) __attribute__((amdgpu_waves_per_eu(2, 2)))
void recurrence(
    const float* __restrict__ whh_f, const float* __restrict__ whh_b,
    const float* __restrict__ h0, const float* __restrict__ c0,
    const float* __restrict__ ZX, float* __restrict__ HALL) {
  const int dir = blockIdx.x;
  const int t = threadIdx.x;
  const int w = t >> 6;            // wave 0..7
  const int l = t & 63;
  const int lcol = l & 15;
  const int lq = l >> 4;           // quadrant 0..3
  const bool hi = (lq >= 2);       // this lane's half
  const int u = (w << 5) + (hi ? 16 : 0) + lcol;   // this lane's unit
  const float* __restrict__ Whh = dir ? whh_b : whh_f;
  const float* __restrict__ Z = ZX + (size_t)dir * LL * NGATE;
  float* __restrict__ Hall = HALL + (size_t)dir * LL * HH;

  __shared__ uint4 WL[8 * 19 * 64];                 // 152 KB LDS B-frags
  __shared__ __align__(16) unsigned h16u[2 * 128];  // packed f16 h, parity dbuf

  // ---- preamble: build B-frags (f32 -> f16 RTZ) --------------------------
  v8h rT0[8], rT2[8], rT4[8], rT6[8];   // even tiles (half 0), reg-resident
  v8h rT1[3], rT3[3], rT7[3];           // odd tiles kc 5-7
  v8h rT5[4];                           // T5 kc 4-7
#pragma unroll
  for (int kc = 0; kc < 8; ++kc) {
#pragma unroll
    for (int T = 0; T < 8; ++T) {
      const int n = ((T >> 1) << 8) + (w << 5) + ((T & 1) << 4) + lcol;
      const float* wp = Whh + (size_t)n * HH + (kc << 5) + (lq << 3);
      const float4 a4 = *reinterpret_cast<const float4*>(wp);
      const float4 b4 = *reinterpret_cast<const float4*>(wp + 4);
      const v8h f = make_v8h(pack_h2(a4.x, a4.y), pack_h2(a4.z, a4.w),
                             pack_h2(b4.x, b4.y), pack_h2(b4.z, b4.w));
      if (T == 0) rT0[kc] = f;
      else if (T == 1) { if (kc < 5) WL[(w * 19 + 0 + kc) * 64 + l] = __builtin_bit_cast(uint4, f); else rT1[kc - 5] = f; }
      else if (T == 2) rT2[kc] = f;
      else if (T == 3) { if (kc < 5) WL[(w * 19 + 5 + kc) * 64 + l] = __builtin_bit_cast(uint4, f); else rT3[kc - 5] = f; }
      else if (T == 4) rT4[kc] = f;
      else if (T == 5) { if (kc < 4) WL[(w * 19 + 15 + kc) * 64 + l] = __builtin_bit_cast(uint4, f); else rT5[kc - 4] = f; }
      else if (T == 6) rT6[kc] = f;
      else             { if (kc < 5) WL[(w * 19 + 10 + kc) * 64 + l] = __builtin_bit_cast(uint4, f); else rT7[kc - 5] = f; }
    }
  }

  // ---- state init --------------------------------------------------------
  float c_reg = c0[dir * HH + u];       // per-lane half state
  if (t < 128)
    h16u[t] = pack_u(h0[dir * HH + 2 * t], h0[dir * HH + 2 * t + 1]);

  // running row pointers (walk instead of per-step multiply)
  const int zstride = dir ? -NGATE : NGATE;
  const int hstride = dir ? -HH : HH;
  const float* zrow = Z + (size_t)(dir ? (LL - 1) : 0) * NGATE;
  float* hrow = Hall + (size_t)(dir ? (LL - 1) : 0) * HH;

  float4 zx = *reinterpret_cast<const float4*>(zrow + 4 * u);
  __syncthreads();

  const char* h16b = reinterpret_cast<const char*>(h16u);

  for (int s = 0; s < LL; ++s) {
    const int par = s & 1;
    const int npar = par ^ 1;
    // prefetch next step's Zx (unconditional pointer walk; final over-read
    // lands in the adjacent direction's valid rows and is never used)
    zrow += zstride;
    const float4 nzx = *reinterpret_cast<const float4*>(zrow + 4 * u);

    const uint4* hq = reinterpret_cast<const uint4*>(h16b + (par << 9));

    // ---- block A: gates i (T0,T1) and f (T2,T3) --------------------------
    v4f aI0 = {0.f,0.f,0.f,0.f}, aI1 = {0.f,0.f,0.f,0.f};
    v4f aF0 = {0.f,0.f,0.f,0.f}, aF1 = {0.f,0.f,0.f,0.f};
#pragma unroll
    for (int kc = 0; kc < 8; ++kc) {
      const v8h ah = __builtin_bit_cast(v8h, hq[(kc << 2) + lq]);
      aI0 = __builtin_amdgcn_mfma_f32_16x16x32_f16(ah, rT0[kc], aI0, 0, 0, 0);
      const v8h bI = (kc < 5) ? __builtin_bit_cast(v8h, WL[(w * 19 + 0 + kc) * 64 + l]) : rT1[kc - 5];
      aI1 = __builtin_amdgcn_mfma_f32_16x16x32_f16(ah, bI, aI1, 0, 0, 0);
      aF0 = __builtin_amdgcn_mfma_f32_16x16x32_f16(ah, rT2[kc], aF0, 0, 0, 0);
      const v8h bF = (kc < 5) ? __builtin_bit_cast(v8h, WL[(w * 19 + 5 + kc) * 64 + l]) : rT3[kc - 5];
      aF1 = __builtin_amdgcn_mfma_f32_16x16x32_f16(ah, bF, aF1, 0, 0, 0);
    }
    // gates i,f start here — no dependency on block B's MFMAs, so the
    // scheduler overlaps these trans-chains with block B's MFMA issue.
    const float zi = zx.x + (hi ? aI1[0] : aI0[0]);
    const float zf = zx.y + (hi ? aF1[0] : aF0[0]);
    const float ig = fsigmoid(zi);
    const float fg = fsigmoid(zf);

    // ---- block B: gates o (T6,T7) and g (T4,T5) --------------------------
    v4f aO0 = {0.f,0.f,0.f,0.f}, aO1 = {0.f,0.f,0.f,0.f};
    v4f aG0 = {0.f,0.f,0.f,0.f}, aG1 = {0.f,0.f,0.f,0.f};
#pragma unroll
    for (int kc = 0; kc < 8; ++kc) {
      const v8h ah = __builtin_bit_cast(v8h, hq[(kc << 2) + lq]);
      aO0 = __builtin_amdgcn_mfma_f32_16x16x32_f16(ah, rT6[kc], aO0, 0, 0, 0);
      const v8h bO = (kc < 5) ? __builtin_bit_cast(v8h, WL[(w * 19 + 10 + kc) * 64 + l]) : rT7[kc - 5];
      aO1 = __builtin_amdgcn_mfma_f32_16x16x32_f16(ah, bO, aO1, 0, 0, 0);
      aG0 = __builtin_amdgcn_mfma_f32_16x16x32_f16(ah, rT4[kc], aG0, 0, 0, 0);
      const v8h bG = (kc < 4) ? __builtin_bit_cast(v8h, WL[(w * 19 + 15 + kc) * 64 + l]) : rT5[kc - 4];
      aG1 = __builtin_amdgcn_mfma_f32_16x16x32_f16(ah, bG, aG1, 0, 0, 0);
    }
    const float zo = zx.w + (hi ? aO1[0] : aO0[0]);
    const float zg = zx.z + (hi ? aG1[0] : aG0[0]);
    const float og = fsigmoid(zo);
    const float gg = ftanh(zg);
    c_reg = fg * c_reg + ig * gg;
    const float hval = og * ftanh(c_reg);

    if ((lq & 1) == 0) hrow[u] = hval;           // lq 0 stores u0, lq 2 stores u1
    // pack (h[2i], h[2i+1]) via lcol^1 neighbor swap (l^1 within quad+half)
    const float nb = dpp_f<0xB1>(hval);
    if ((lq & 1) == 0 && (lcol & 1) == 0)
      h16u[(npar << 7) + (w << 4) + (hi ? 8 : 0) + (lcol >> 1)] = pack_u(hval, nb);
    __syncthreads();
    zx = nzx;
    hrow += hstride;
  }
}

// ---------------------------------------------------------------------------
// Kernel 4: feats
// ---------------------------------------------------------------------------
__global__ __launch_bounds__(256) void feats_gemm(
    const float* __restrict__ HALL, const float* __restrict__ Wout,
    const float* __restrict__ bout, float* __restrict__ FE) {
  __shared__ float Wl[16][516];
  const int t = threadIdx.x;
  for (int i = t; i < 16 * 512; i += 256) Wl[i >> 9][i & 511] = Wout[i];
  __syncthreads();
  const int row = blockIdx.x * 16 + (t >> 4);
  const int j = t & 15;
  const float* hf = HALL + (size_t)row * HH;
  const float* hb = HALL + (size_t)LL * HH + (size_t)row * HH;
  float acc = bout[j];
  for (int k = 0; k < HH; k += 4) {
    const float4 a = *reinterpret_cast<const float4*>(hf + k);
    const float4 wa = *reinterpret_cast<const float4*>(&Wl[j][k]);
    acc += a.x * wa.x + a.y * wa.y + a.z * wa.z + a.w * wa.w;
    const float4 b2 = *reinterpret_cast<const float4*>(hb + k);
    const float4 wb = *reinterpret_cast<const float4*>(&Wl[j][256 + k]);
    acc += b2.x * wb.x + b2.y * wb.y + b2.z * wb.z + b2.w * wb.w;
  }
  FE[(size_t)row * TT + j] = acc;
}

// ---------------------------------------------------------------------------
// Kernel 5: Viterbi (unchanged)
// ---------------------------------------------------------------------------
__global__ __launch_bounds__(1024) void viterbi(
    const float* __restrict__ FE, const float* __restrict__ trans,
    float* __restrict__ out) {
  __shared__ unsigned char bp8[LL * TT];
  __shared__ unsigned char xc[64 * 16];
  __shared__ unsigned char entry[64];
  __shared__ int sbest;
  const int t = threadIdx.x;

  if (t < 64) {
    const int n = t >> 2, pg = t & 3;
    const float tr0 = trans[n * 16 + (pg << 2) + 0];
    const float tr1 = trans[n * 16 + (pg << 2) + 1];
    const float tr2 = trans[n * 16 + (pg << 2) + 2];
    const float tr3 = trans[n * 16 + (pg << 2) + 3];
    float fvp0 = ((pg << 2) + 0 == 14) ? 0.f : NEGV;
    float fvp1 = ((pg << 2) + 1 == 14) ? 0.f : NEGV;
    float fvp2 = ((pg << 2) + 2 == 14) ? 0.f : NEGV;
    float fvp3 = ((pg << 2) + 3 == 14) ? 0.f : NEGV;

    auto step = [&](int s, float feat) {
      float bv = fvp0 + tr0; int bi = (pg << 2);
      float c;
      c = fvp1 + tr1; if (c > bv) { bv = c; bi = (pg << 2) + 1; }
      c = fvp2 + tr2; if (c > bv) { bv = c; bi = (pg << 2) + 2; }
      c = fvp3 + tr3; if (c > bv) { bv = c; bi = (pg << 2) + 3; }
      float pv = dpp_f<0xB1>(bv); int pi = dpp_i<0xB1>(bi);
      if (pv > bv || (pv == bv && pi < bi)) { bv = pv; bi = pi; }
      pv = dpp_f<0x4E>(bv); pi = dpp_i<0x4E>(bi);
      if (pv > bv || (pv == bv && pi < bi)) { bv = pv; bi = pi; }
      if (pg == 0) bp8[(s << 4) + n] = (unsigned char)bi;
      const float fvn = bv + feat;
      fvp0 = bperm_f((pg << 4) + 0,  fvn);
      fvp1 = bperm_f((pg << 4) + 4,  fvn);
      fvp2 = bperm_f((pg << 4) + 8,  fvn);
      fvp3 = bperm_f((pg << 4) + 12, fvn);
    };

    float fb0 = FE[(0 << 4) + n], fb1 = FE[(1 << 4) + n];
    float fb2 = FE[(2 << 4) + n], fb3 = FE[(3 << 4) + n];
    for (int s = 0; s < LL; s += 4) {
      step(s + 0, fb0); fb0 = (s + 4 < LL) ? FE[((s + 4) << 4) + n] : 0.f;
      step(s + 1, fb1); fb1 = (s + 5 < LL) ? FE[((s + 5) << 4) + n] : 0.f;
      step(s + 2, fb2); fb2 = (s + 6 < LL) ? FE[((s + 6) << 4) + n] : 0.f;
      step(s + 3, fb3); fb3 = (s + 7 < LL) ? FE[((s + 7) << 4) + n] : 0.f;
    }

    const float tt0 = trans[240 + (pg << 2) + 0];
    const float tt1 = trans[240 + (pg << 2) + 1];
    const float tt2 = trans[240 + (pg << 2) + 2];
    const float tt3 = trans[240 + (pg << 2) + 3];
    float bv = fvp0 + tt0; int bi = (pg << 2);
    float c;
    c = fvp1 + tt1; if (c > bv) { bv = c; bi = (pg << 2) + 1; }
    c = fvp2 + tt2; if (c > bv) { bv = c; bi = (pg << 2) + 2; }
    c = fvp3 + tt3; if (c > bv) { bv = c; bi = (pg << 2) + 3; }
    float pv = dpp_f<0xB1>(bv); int pi = dpp_i<0xB1>(bi);
    if (pv > bv || (pv == bv && pi < bi)) { bv = pv; bi = pi; }
    pv = dpp_f<0x4E>(bv); pi = dpp_i<0x4E>(bi);
    if (pv > bv || (pv == bv && pi < bi)) { bv = pv; bi = pi; }
    if (t == 0) { out[0] = bv; sbest = bi; }
  }
  __syncthreads();

  {
    const int c = t >> 4, e = t & 15;
    int tag = e;
#pragma unroll 1
    for (int i = 63; i >= 0; --i) tag = bp8[(((c << 6) + i) << 4) + tag];
    xc[(c << 4) + e] = (unsigned char)tag;
  }
  __syncthreads();
  if (t == 0) {
    int carry = sbest;
#pragma unroll 1
    for (int c = 63; c >= 0; --c) {
      entry[c] = (unsigned char)carry;
      carry = xc[(c << 4) + carry];
    }
  }
  __syncthreads();
  if (t < 64) {
    const int c = t;
    int tag = entry[c];
#pragma unroll 1
    for (int i = 63; i >= 0; --i) {
      const int s = (c << 6) + i;
      out[1 + s] = (float)tag;
      tag = bp8[(s << 4) + tag];
    }
  }
}

// ---------------------------------------------------------------------------
extern "C" void kernel_launch(void* const* d_in, const int* in_sizes, int n_in,
                              void* d_out, int out_size, void* d_ws, size_t ws_size,
                              hipStream_t stream) {
  const int*   sent = (const int*)d_in[0];
  const float* emb  = (const float*)d_in[1];
  const float* wihf = (const float*)d_in[2];
  const float* whhf = (const float*)d_in[3];
  const float* bf   = (const float*)d_in[4];
  const float* wihb = (const float*)d_in[5];
  const float* whhb = (const float*)d_in[6];
  const float* bb   = (const float*)d_in[7];
  const float* wout = (const float*)d_in[8];
  const float* bout = (const float*)d_in[9];
  const float* trans= (const float*)d_in[10];
  const float* h0   = (const float*)d_in[11];
  const float* c0   = (const float*)d_in[12];
  float* out = (float*)d_out;
  char* ws = (char*)d_ws;

  float* X    = (float*)(ws + OFF_X);
  float* ZX   = (float*)(ws + OFF_ZX);
  float* HALL = (float*)(ws + OFF_HALL);
  float* FE   = (float*)(ws + OFF_FE);

  gather_x<<<(LL * (EE / 4) + 255) / 256, 256, 0, stream>>>(sent, emb, X);
  input_gemm<<<dim3(16, 64, 2), 256, 0, stream>>>(X, wihf, bf, wihb, bb, ZX);
  recurrence<<<2, 512, 0, stream>>>(whhf, whhb, h0, c0, ZX, HALL);
  feats_gemm<<<LL / 16, 256, 0, stream>>>(HALL, wout, bout, FE);
  viterbi<<<1, 1024, 0, stream>>>(FE, trans, out);
}